// Round 5
// baseline (1426.742 us; speedup 1.0000x reference)
//
#include <hip/hip_runtime.h>
#include <stdint.h>

#define AS1 __attribute__((address_space(1)))
#define AS3 __attribute__((address_space(3)))

typedef unsigned short u16;
typedef __attribute__((ext_vector_type(8))) short s16x8;
typedef __attribute__((ext_vector_type(8))) unsigned short u16x8;
typedef __attribute__((ext_vector_type(4))) float f32x4;

__device__ __forceinline__ u16 f2bf(float f) {
    union { float f; unsigned int u; } v; v.f = f;
    unsigned int r = v.u + 0x7fffu + ((v.u >> 16) & 1u);
    return (u16)(r >> 16);
}

// async global->LDS, 16B per lane. LDS dest = wave-uniform base + lane*16.
__device__ __forceinline__ void gld_lds16(const u16* g, u16* l) {
    __builtin_amdgcn_global_load_lds((AS1 unsigned int*)(uintptr_t)g,
                                     (AS3 unsigned int*)(uintptr_t)l, 16, 0, 0);
}

// ---------------- convert x: fp32 -> bf16 ----------------
__global__ void convert_x_kernel(const float* __restrict__ X, u16* __restrict__ Xb, int total8) {
    int i = blockIdx.x * 256 + threadIdx.x;
    if (i < total8) {
        f32x4 a = ((const f32x4*)X)[2 * i];
        f32x4 b = ((const f32x4*)X)[2 * i + 1];
        u16x8 o;
#pragma unroll
        for (int j = 0; j < 4; j++) { o[j] = f2bf(a[j]); o[4 + j] = f2bf(b[j]); }
        ((u16x8*)Xb)[i] = o;
    }
}

// ---------------- gating: gates[n][50] = softmax(x@Wg + bg), all fp32 ----------------
__global__ void gate_kernel(const float* __restrict__ X, const float* __restrict__ Wg,
                            const float* __restrict__ bg, float* __restrict__ gates, int nt) {
    __shared__ float xs[1024];
    const int n = blockIdx.x;
    const int t = threadIdx.x; // 64 threads = 1 wave
#pragma unroll
    for (int i = 0; i < 16; i++) xs[t + i * 64] = X[(size_t)n * 1024 + t + i * 64];
    __syncthreads();
    float a = -INFINITY;
    if (t < 50) {
        float s0 = 0.f, s1 = 0.f, s2 = 0.f, s3 = 0.f;
        for (int d = 0; d < 1024; d += 4) {
            s0 += xs[d + 0] * Wg[(d + 0) * 50 + t];
            s1 += xs[d + 1] * Wg[(d + 1) * 50 + t];
            s2 += xs[d + 2] * Wg[(d + 2) * 50 + t];
            s3 += xs[d + 3] * Wg[(d + 3) * 50 + t];
        }
        a = (s0 + s1) + (s2 + s3) + bg[t];
    }
    float m = a;
#pragma unroll
    for (int off = 32; off > 0; off >>= 1) m = fmaxf(m, __shfl_xor(m, off));
    float p = (t < 50) ? __expf(a - m) : 0.f;
    float ss = p;
#pragma unroll
    for (int off = 32; off > 0; off >>= 1) ss += __shfl_xor(ss, off);
    if (t < 50) gates[(size_t)n * 50 + t] = p / ss;
}

// ------- transpose+convert 1024x1024 fp32 [k][n] -> bf16 [n][k]; z: eg W1 mats then eg W2 mats ----
__global__ void transpose_kernel(const float* __restrict__ W1s, const float* __restrict__ W2s,
                                 u16* __restrict__ Wt1, u16* __restrict__ Wt2, int eg) {
    __shared__ u16 tile[64 * 65];
    const int t = threadIdx.x; // 256
    const int z = blockIdx.z;
    const float* src; u16* dst;
    if (z < eg) { src = W1s + ((size_t)z << 20); dst = Wt1 + ((size_t)z << 20); }
    else        { src = W2s + ((size_t)(z - eg) << 20); dst = Wt2 + ((size_t)(z - eg) << 20); }
    const int k0 = blockIdx.y * 64;
    const int n0 = blockIdx.x * 64;
#pragma unroll
    for (int p = 0; p < 4; p++) {
        int r = (t >> 4) + 16 * p;
        int c = t & 15;
        f32x4 v = *(const f32x4*)(src + (size_t)(k0 + r) * 1024 + n0 + c * 4);
#pragma unroll
        for (int j = 0; j < 4; j++) tile[r * 65 + c * 4 + j] = f2bf(v[j]);
    }
    __syncthreads();
#pragma unroll
    for (int p = 0; p < 2; p++) {
        int h = (t >> 3) + 32 * p;
        int c = t & 7;
        u16x8 o;
#pragma unroll
        for (int j = 0; j < 8; j++) o[j] = tile[(c * 8 + j) * 65 + h];
        *(u16x8*)(dst + (size_t)(n0 + h) * 1024 + k0 + c * 8) = o;
    }
}

// =====================================================================================
// R4: TWO blocks per CU (4 waves / 256 thr each) to break barrier lockstep.
// R2's intra-block phase split proved barriers force all waves of a block into
// simultaneous read-bursts then MFMA-bursts (LDS 1408 cyc + MFMA 1242 cyc serialize
// -> 39% MfmaUtil). Two independent blocks have independent barriers -> block A's
// MFMA overlaps block B's LDS/stage phase.
// Tile 128m x 256n, wave grid 1x4 (per-wave 128x64, acc 32 f32x4 = 128 VGPR).
// 2 waves/SIMD at <=256 unified regs (__launch_bounds__(256,2)).
// BK=32, 3 LDS buffers of 24KB (A 128x32 + B 256x32) = 72KB/block (144KB/CU).
// Prefetch distance 2, counted vmcnt(6) (6 glds/tile), vmcnt 6 -> 6 -> 0 at tail.
// LDS swizzle (R1-verified, 0 conflicts at 64B rows): chunk = fq ^ ((row>>1)&3),
// applied on BOTH sides (pre-swizzled global source + XOR'd ds_read offset).
// Grid order: m innermost => the 4 n-blocks sharing an A-panel are 32 ids apart
// (same XCD under round-robin, 32%8==0) and same-expert B readers are co-temporal
// (weight slice 512KB is L2-resident per XCD).
// =====================================================================================

#define BUF_U16 12288  // per buffer: A 128x32 (4096 u16) + B 256x32 (8192 u16) = 24KB

#define STG1(t) { int bo = ((t) % 3) * BUF_U16;                                   \
        const u16* a = Ag + (t) * 32; const u16* b = Bg + (t) * 32;               \
        gld_lds16(a,          Al + bo);                                           \
        gld_lds16(a + 65536,  Al + bo + 2048);                                    \
        gld_lds16(b,          Bl + bo);                                           \
        gld_lds16(b + 65536,  Bl + bo + 2048);                                    \
        gld_lds16(b + 131072, Bl + bo + 4096);                                    \
        gld_lds16(b + 196608, Bl + bo + 6144); }

#define STG2(t) { int kt = kb + (t) * 32; int ee = kt >> 10; int kk = kt & 1023;  \
        const u16* a = Agr + (size_t)ee * ntk + kk;                               \
        const u16* b = Bgr + ((size_t)ee << 20) + kk;                             \
        int bo = ((t) % 3) * BUF_U16;                                             \
        gld_lds16(a,          Al + bo);                                           \
        gld_lds16(a + 65536,  Al + bo + 2048);                                    \
        gld_lds16(b,          Bl + bo);                                           \
        gld_lds16(b + 65536,  Bl + bo + 2048);                                    \
        gld_lds16(b + 131072, Bl + bo + 4096);                                    \
        gld_lds16(b + 196608, Bl + bo + 6144); }

#define MMSTEP(t, VM, DO, STG) {                                                  \
        asm volatile("s_waitcnt vmcnt(" VM ")\n\ts_barrier" ::: "memory");        \
        if (DO) STG((t) + 2);                                                     \
        const u16* bp = smem + ((t) % 3) * BUF_U16;                               \
        s16x8 av[8], bv[4];                                                       \
        _Pragma("unroll") for (int mi = 0; mi < 8; mi++)                          \
            av[mi] = *(const s16x8*)(bp + aoff[mi]);                              \
        _Pragma("unroll") for (int nj = 0; nj < 4; nj++)                          \
            bv[nj] = *(const s16x8*)(bp + boff[nj]);                              \
        __builtin_amdgcn_s_setprio(1);                                            \
        _Pragma("unroll") for (int mi = 0; mi < 8; mi++)                          \
        _Pragma("unroll") for (int nj = 0; nj < 4; nj++)                          \
            acc[mi * 4 + nj] = __builtin_amdgcn_mfma_f32_16x16x32_bf16(           \
                av[mi], bv[nj], acc[mi * 4 + nj], 0, 0, 0);                       \
        __builtin_amdgcn_s_setprio(0); }

// ---------------- gemm1: Hp[e] = bf16( gates[:,e] * relu(Xb @ W1t[e] + b1[e]) ) ----------
__global__ __launch_bounds__(256, 2)
void gemm1_kernel(const u16* __restrict__ X, const u16* __restrict__ Wt1,
                  const float* __restrict__ b1, const float* __restrict__ gates,
                  u16* __restrict__ Hp, int nt, int egbase) {
    __shared__ __align__(16) u16 smem[36864]; // 3 bufs (72KB); epilogue C-tile 128x264 (66KB)
    const int tid = threadIdx.x, wave = tid >> 6, lane = tid & 63;
    const int e = blockIdx.z;
    const int m0 = blockIdx.x * 128, n0 = blockIdx.y * 256;

    // staging: thread covers rows srow/+64 (A) and srow/+64/+128/+192 (B), 16B chunks,
    // pre-swizzled source. (row>>1)&3 is invariant under +64 so scg is per-thread const.
    const int srow = wave * 16 + (lane >> 2);
    const int scg = ((lane & 3) ^ ((srow >> 1) & 3)) * 8;
    const u16* Ag = X + (size_t)(m0 + srow) * 1024 + scg;
    const u16* Bg = Wt1 + ((size_t)e << 20) + (size_t)(n0 + srow) * 1024 + scg;
    u16* Al = smem + wave * 512;
    u16* Bl = smem + 4096 + wave * 512;

    const int fr = lane & 15, fq = lane >> 4;
    int aoff[8], boff[4];
#pragma unroll
    for (int mi = 0; mi < 8; mi++) {
        int ra = mi * 16 + fr;
        aoff[mi] = ra * 32 + ((fq ^ ((ra >> 1) & 3)) * 8);
    }
#pragma unroll
    for (int nj = 0; nj < 4; nj++) {
        int rb = wave * 64 + nj * 16 + fr;
        boff[nj] = 4096 + rb * 32 + ((fq ^ ((rb >> 1) & 3)) * 8);
    }

    f32x4 acc[32];
#pragma unroll
    for (int i = 0; i < 32; i++) acc[i] = (f32x4){0.f, 0.f, 0.f, 0.f};

    STG1(0); STG1(1);
    for (int t = 0; t < 30; ++t) MMSTEP(t, "6", 1, STG1);
    MMSTEP(30, "6", 0, STG1);
    MMSTEP(31, "0", 0, STG1);

    // epilogue: bias + relu + gate, bounce through LDS for coalesced bf16 stores
    const float* b1e = b1 + (size_t)e * 1024;
    float b1v[4];
#pragma unroll
    for (int nj = 0; nj < 4; nj++) b1v[nj] = b1e[n0 + wave * 64 + nj * 16 + fr];
    const int eglob = egbase + e;

    __syncthreads(); // done with bufs; reuse smem as C tile (stride 264)
#pragma unroll
    for (int mi = 0; mi < 8; mi++) {
#pragma unroll
        for (int ri = 0; ri < 4; ri++) {
            int row = mi * 16 + fq * 4 + ri;
            float g = gates[(size_t)(m0 + row) * 50 + eglob];
#pragma unroll
            for (int nj = 0; nj < 4; nj++) {
                int col = wave * 64 + nj * 16 + fr;
                float h = acc[mi * 4 + nj][ri] + b1v[nj];
                h = h > 0.f ? h * g : 0.f;
                smem[row * 264 + col] = f2bf(h);
            }
        }
    }
    __syncthreads();
    u16* HpE = Hp + (size_t)e * nt * 1024;
    const int c = tid & 31, rr = tid >> 5;
#pragma unroll
    for (int p = 0; p < 16; p++) {
        int r = rr + p * 8;
        u16x8 v = *(const u16x8*)(smem + r * 264 + c * 8);
        *(u16x8*)(HpE + (size_t)(m0 + r) * 1024 + n0 + c * 8) = v;
    }
}

// ---------------- gemm2: partial[s] (+)= slice_s( sum_e Hp[e] @ W2t[e] ), s in 0..3 ----------
__global__ __launch_bounds__(256, 2)
void gemm2_kernel(const u16* __restrict__ Hp, const u16* __restrict__ Wt2,
                  float* __restrict__ partial, int nt, int eg, int init) {
    __shared__ __align__(16) u16 smem[36864]; // 3 bufs = 72KB
    const int tid = threadIdx.x, wave = tid >> 6, lane = tid & 63;
    const int s = blockIdx.z;
    const int m0 = blockIdx.x * 128, n0 = blockIdx.y * 256;

    const int srow = wave * 16 + (lane >> 2);
    const int scg = ((lane & 3) ^ ((srow >> 1) & 3)) * 8;
    const u16* Agr = Hp + (size_t)(m0 + srow) * 1024 + scg;
    const u16* Bgr = Wt2 + (size_t)(n0 + srow) * 1024 + scg;
    const size_t ntk = (size_t)nt * 1024;
    u16* Al = smem + wave * 512;
    u16* Bl = smem + 4096 + wave * 512;

    const int fr = lane & 15, fq = lane >> 4;
    int aoff[8], boff[4];
#pragma unroll
    for (int mi = 0; mi < 8; mi++) {
        int ra = mi * 16 + fr;
        aoff[mi] = ra * 32 + ((fq ^ ((ra >> 1) & 3)) * 8);
    }
#pragma unroll
    for (int nj = 0; nj < 4; nj++) {
        int rb = wave * 64 + nj * 16 + fr;
        boff[nj] = 4096 + rb * 32 + ((fq ^ ((rb >> 1) & 3)) * 8);
    }

    f32x4 acc[32];
#pragma unroll
    for (int i = 0; i < 32; i++) acc[i] = (f32x4){0.f, 0.f, 0.f, 0.f};

    const int NT = eg * 8;       // K-tiles of 32 in this slice (eg*1024/4/32)
    const int kb = s * NT * 32;  // absolute k start of slice

    STG2(0); STG2(1);
    for (int t = 0; t < NT - 2; ++t) MMSTEP(t, "6", 1, STG2);
    MMSTEP(NT - 2, "6", 0, STG2);
    MMSTEP(NT - 1, "0", 0, STG2);

    float* pp = partial + (size_t)s * nt * 1024;
#pragma unroll
    for (int mi = 0; mi < 8; mi++) {
#pragma unroll
        for (int ri = 0; ri < 4; ri++) {
            int gr = m0 + mi * 16 + fq * 4 + ri;
#pragma unroll
            for (int nj = 0; nj < 4; nj++) {
                size_t idx = (size_t)gr * 1024 + n0 + wave * 64 + nj * 16 + fr;
                float v = acc[mi * 4 + nj][ri];
                if (!init) v += pp[idx];
                pp[idx] = v;
            }
        }
    }
}

// ---------------- finalize: out = sum_s partial[s] + sum_e gates*b2, fp32 out ----------------
__global__ void finalize_kernel(const float* __restrict__ partial, const float* __restrict__ gates,
                                const float* __restrict__ b2, float* __restrict__ out, int nt) {
    __shared__ float gs[50];
    const int n = blockIdx.x;
    const int t = threadIdx.x; // 256
    if (t < 50) gs[t] = gates[(size_t)n * 50 + t];
    __syncthreads();
    const size_t base = (size_t)n * 1024;
    const size_t st = (size_t)nt * 1024;
#pragma unroll
    for (int i = 0; i < 4; i++) {
        int d = t + i * 256;
        float v = partial[base + d] + partial[st + base + d]
                + partial[2 * st + base + d] + partial[3 * st + base + d];
#pragma unroll 10
        for (int e2 = 0; e2 < 50; e2++) v += gs[e2] * b2[e2 * 1024 + d];
        out[base + d] = v;
    }
}

extern "C" void kernel_launch(void* const* d_in, const int* in_sizes, int n_in,
                              void* d_out, int out_size, void* d_ws, size_t ws_size,
                              hipStream_t stream) {
    const float* x  = (const float*)d_in[0];
    const float* W1 = (const float*)d_in[1];
    const float* b1 = (const float*)d_in[2];
    const float* W2 = (const float*)d_in[3];
    const float* b2 = (const float*)d_in[4];
    const float* Wg = (const float*)d_in[5];
    const float* bg = (const float*)d_in[6];
    float* out = (float*)d_out;
    const int nt = in_sizes[0] / 1024; // 4096

    char* w = (char*)d_ws;
    auto carve = [&](size_t bytes) -> char* {
        char* p = w; w += (bytes + 255) & ~(size_t)255; return p;
    };
    float* gates   = (float*)carve((size_t)nt * 50 * 4);
    float* partial = (float*)carve((size_t)4 * nt * 1024 * 4);
    u16*   xb      = (u16*)carve((size_t)nt * 1024 * 2);
    const size_t fixed = (size_t)(w - (char*)d_ws);

    int eg = 1;
    const int cand[6] = {50, 25, 10, 5, 2, 1};
    for (int i = 0; i < 6; i++) {
        size_t need = fixed + (size_t)cand[i] * ((size_t)2 * 2097152 + (size_t)nt * 1024 * 2) + 4096;
        if (need <= ws_size) { eg = cand[i]; break; }
    }
    u16* Wt1 = (u16*)carve((size_t)eg * 1048576 * 2);
    u16* Wt2 = (u16*)carve((size_t)eg * 1048576 * 2);
    u16* Hp  = (u16*)carve((size_t)eg * nt * 1024 * 2);

    convert_x_kernel<<<(nt * 1024 / 8 + 255) / 256, 256, 0, stream>>>(x, xb, nt * 1024 / 8);
    gate_kernel<<<nt, 64, 0, stream>>>(x, Wg, bg, gates, nt);

    const int groups = 50 / eg;
    for (int g = 0; g < groups; ++g) {
        transpose_kernel<<<dim3(16, 16, 2 * eg), 256, 0, stream>>>(
            W1 + ((size_t)(g * eg) << 20), W2 + ((size_t)(g * eg) << 20), Wt1, Wt2, eg);
        gemm1_kernel<<<dim3(nt / 128, 4, eg), 256, 0, stream>>>(
            xb, Wt1, b1 + (size_t)g * eg * 1024, gates, Hp, nt, g * eg);
        gemm2_kernel<<<dim3(nt / 128, 4, 4), 256, 0, stream>>>(
            Hp, Wt2, partial, nt, eg, g == 0 ? 1 : 0);
    }
    finalize_kernel<<<nt, 256, 0, stream>>>(partial, gates, b2, out, nt);
}